// Round 7
// baseline (500.287 us; speedup 1.0000x reference)
//
#include <hip/hip_runtime.h>
#include <hip/hip_bf16.h>
#include <cstdint>

typedef __attribute__((ext_vector_type(8))) short bf16x8;
typedef __attribute__((ext_vector_type(4))) float f32x4;

#define H_DIM 1024
#define B_DIM 32
#define L_DIM 2048
#define NT 32                   // K-tiles of 64 (K_TOT = 2048)

__device__ __forceinline__ void gload16(const void* g, void* l) {
  __builtin_amdgcn_global_load_lds(
      (const __attribute__((address_space(1))) unsigned int*)g,
      (__attribute__((address_space(3))) unsigned int*)l, 16, 0, 0);
}

#define VMCNT(n) asm volatile("s_waitcnt vmcnt(" #n ")" ::: "memory")
#define LGKM0 asm volatile("s_waitcnt lgkmcnt(0)" ::: "memory")
#define SBAR __builtin_amdgcn_sched_barrier(0)
#define BAR do { SBAR; __builtin_amdgcn_s_barrier(); SBAR; } while (0)

// fast tanh: 1 - 2/(exp(2x)+1). Saturates correctly; no NaN. Validated R12.
__device__ __forceinline__ float tanh_fast(float x) {
  return 1.f - 2.f / (__expf(2.f * x) + 1.f);
}

// ---------------------------------------------------------------- weights-only convert (8 MB traffic, ~3 us)
__global__ void __launch_bounds__(256)
convert_w(const float* __restrict__ Wk, const float* __restrict__ Wq,
          __hip_bfloat16* __restrict__ wkb, __hip_bfloat16* __restrict__ wqb) {
  const int i = blockIdx.x * 256 + threadIdx.x;   // 0..524287 float4 chunks
  const float* src = (i < 262144) ? Wk : Wq;
  __hip_bfloat16* dst = (i < 262144) ? wkb : wqb;
  const int off = i & 262143;
  float4 v = ((const float4*)src)[off];
  __hip_bfloat16 h[4];
  h[0] = __float2bfloat16(v.x);
  h[1] = __float2bfloat16(v.y);
  h[2] = __float2bfloat16(v.z);
  h[3] = __float2bfloat16(v.w);
  *(uint2*)(dst + (size_t)off * 4) = *(const uint2*)h;
}

// ---------------------------------------------------------------- 256x256x64 8-wave GEMM (R18: f32 A via LDS scratch + in-pipe cvt)
// R11 phase skeleton; A-path now consumes f32 key/query directly:
//   gload_lds stages f32 A-halves (32KB) into scratch bufs (fire-and-forget,
//   no register deadline — unlike the failed R13-R16 reg-staging), then an
//   LDS->LDS cvt pass (read own staged chunks, RNE cvt, swizzled b64 writes)
//   produces the bf16 A-halves the frag reads consume. cvt is a LOCAL
//   producer: every consumer is >=1 barrier away; scratch dbuf gives the
//   gload a 3-phase runway.
// LDS (128 KiB): A-bf16 SINGLE buffer [kk][256][32] @0 (cvt overwrites half
// kk one barrier after its last frag read); B-bf16 SINGLE buffer @32768
// (stage B(kk,t+1) issues at P2/P4, after that half's last read at P1/P3);
// f32 scratch @65536: buf kk at +kk*32768, [256][32] f32 linear.
// Swizzle (A & B, 16B units): byte ^= ((byte>>7)&3)<<4 — conflict-free for
// the 16x16 frag pattern (R5 lesson); cvt's 8B writes only need bits>=4.
// Schedule per tile t (stages: F=f32 A-half gload(4), B=bf16 B-half gload(2)):
//   P1: frags A[kk0]m0-3 + B[kk0]; VMCNT(6)  [drain F1(t)]; CVT A(t,kk1)
//       from buf1; LGKM0; BAR; MFMA.
//   P2: frags A[kk0]m4-7; stage B(kk0,t+1), F(kk1,t+1)->buf1; VMCNT(10)
//       [drain B1(t)]; BAR; MFMA.
//   P3: frags A[kk1]m0-3 + B[kk1]; VMCNT(6) [drain F0(t+1)]; CVT A(t+1,kk0)
//       from buf0; LGKM0; BAR; MFMA.
//   P4: frags A[kk1]m4-7; stage B(kk1,t+1), F(kk0,t+2)->buf0; VMCNT(10)
//       [drain B0(t+1)]; BAR; MFMA.
// Invariant entering P1(t): outstanding = [F1(t)x4, B1(t)x2, F0(t+1)x4].
// All deadlines >=2 phases; never drains to 0 mid-loop; depth 6-12 ops.
// WAR: A[kk] overwritten by cvt exactly 1 barrier after its last frag read;
// scratch buf re-issued 1 barrier after its cvt read; B half staged after
// its last read same-tile. Tail: PEN skips F(kk0,NT)@P4 (W4=VMCNT(6));
// LAST: W1=VMCNT(2), W2=VMCNT(0), no P3-cvt, no stages.
__global__ void __launch_bounds__(512, 2)
gemm_score_kernel(const float* __restrict__ key,
                  const float* __restrict__ query,
                  const __hip_bfloat16* __restrict__ wkb,
                  const __hip_bfloat16* __restrict__ wqb,
                  const float* __restrict__ bias,
                  const float* __restrict__ w_score,
                  float* __restrict__ spart) {
  extern __shared__ __align__(1024) char lds[];

  // bijective XCD swizzle: nwg=1024 (%8==0), chunk=128
  const int d = blockIdx.x;
  const int orig = (d & 7) * 128 + (d >> 3);
  const int mt = orig >> 2;  // 0..255
  const int nt = orig & 3;   // 0..3

  const int tid = threadIdx.x;
  const int lane = tid & 63;
  const int w = tid >> 6;
  const int wr = w >> 2;     // 0..1
  const int wc = w & 3;      // 0..3

  // ---- B staging precompute (gload, pre-swizzled bf16 source, linear dest)
  int dstoff[2];
  size_t boffg[2];
#pragma unroll
  for (int i = 0; i < 2; ++i) {
    int p = (i * 512 + tid) * 16;
    int row = p >> 6;                       // 0..255
    int q = p ^ (((p >> 7) & 3) << 4);
    dstoff[i] = p;
    boffg[i] = (size_t)(nt * 256 + row) * 1024 + ((q & 63) >> 1);
  }

  // ---- F32 A staging + cvt precompute. Thread owns scratch chunks
  // c = j*512+tid (j=0..3): r=c>>3 (row), pos=c&7 (16B k-slot).
  size_t fsrc[4];     // global f32 offset (row*1024 + pos*4), + kb at issue
  int scroff[4];      // scratch byte offset (linear, = gload dest)
  int cvtoff[4];      // swizzled bf16 dest byte offset within 16KB half
#pragma unroll
  for (int j = 0; j < 4; ++j) {
    int c = j * 512 + tid;
    int r = c >> 3, pos = c & 7;
    fsrc[j] = (size_t)(mt * 256 + r) * 1024 + pos * 4;
    scroff[j] = c * 16;
    int byte = r * 64 + pos * 8;
    cvtoff[j] = byte ^ (((byte >> 7) & 3) << 4);
  }

#define STAGE_F(kk, tt) do {                                                   \
    const float* sp_ = ((tt) * 64 < 1024) ? key : query;                       \
    const int kb_ = (((tt) * 64) & 1023) + (kk) * 32;                          \
    char* db_ = lds + 65536 + (kk) * 32768;                                    \
    _Pragma("unroll") for (int j = 0; j < 4; ++j)                              \
      gload16(sp_ + fsrc[j] + kb_, db_ + scroff[j]);                           \
  } while (0)
#define CVT_A(kk) do {                                                         \
    const char* sb_ = lds + 65536 + (kk) * 32768;                              \
    _Pragma("unroll") for (int j = 0; j < 4; ++j) {                            \
      f32x4 v = *(const f32x4*)(sb_ + scroff[j]);                              \
      union { __hip_bfloat16 h[4]; uint2 u; } pk;                              \
      pk.h[0] = __float2bfloat16(v[0]);                                        \
      pk.h[1] = __float2bfloat16(v[1]);                                        \
      pk.h[2] = __float2bfloat16(v[2]);                                        \
      pk.h[3] = __float2bfloat16(v[3]);                                        \
      *(uint2*)(lds + (kk) * 16384 + cvtoff[j]) = pk.u;                        \
    }                                                                          \
  } while (0)
#define STAGE_B(kk, tt) do {                                                   \
    const __hip_bfloat16* sp_ = ((tt) * 64 < 1024) ? wkb : wqb;                \
    const int kb_ = (((tt) * 64) & 1023) + (kk) * 32;                          \
    char* db_ = lds + 32768 + (kk) * 16384;                                    \
    gload16(sp_ + boffg[0] + kb_, db_ + dstoff[0]);                            \
    gload16(sp_ + boffg[1] + kb_, db_ + dstoff[1]);                            \
  } while (0)

  // ---- fragment ds_read byte offsets
  const int frow = lane & 15;
  const int koffb = (lane >> 4) * 16;
  int aoff[8][2], boff[4][2];
#pragma unroll
  for (int m = 0; m < 8; ++m) {
    int r = wr * 128 + m * 16 + frow;
#pragma unroll
    for (int kk = 0; kk < 2; ++kk) {
      int byte = r * 64 + koffb;
      aoff[m][kk] = kk * 16384 + (byte ^ (((byte >> 7) & 3) << 4));
    }
  }
#pragma unroll
  for (int n = 0; n < 4; ++n) {
    int r = wc * 64 + n * 16 + frow;
#pragma unroll
    for (int kk = 0; kk < 2; ++kk) {
      int byte = r * 64 + koffb;
      boff[n][kk] = 32768 + kk * 16384 + (byte ^ (((byte >> 7) & 3) << 4));
    }
  }

  f32x4 acc[8][4] = {};

  // ---- prologue. Builds invariant: A[kk0]=cvt'd A(0,kk0); B[kk0] landed;
  // outstanding = [F1(0)x4, B1(0)x2, F0(1)x4] (oldest first).
  STAGE_F(0, 0);            // F(0,kk0) -> buf0   [4]
  STAGE_B(0, 0);            // B(0,kk0)           [2]
  STAGE_F(1, 0);            // F(0,kk1) -> buf1   [4]
  STAGE_B(1, 0);            // B(0,kk1)           [2]
  VMCNT(8);                 // F(0,kk0)+B(0,kk0) landed
  CVT_A(0);                 // A(0,kk0): reads own landed chunks
  LGKM0;                    // cvt reads retired -> buf0 reusable; writes done
  STAGE_F(0, 1);            // F(1,kk0) -> buf0   [4]
  BAR;                      // publish cvt writes

#define TILE_STEP(T, DO_STG, DO_F0, DO_CVT3, W1, W2, W3, W4, DO_BAR4)          \
  do {                                                                         \
    const int t_ = (T);                                                        \
    bf16x8 a0[4], a1[4], b0[4], b1[4];                                         \
    /* P1: frags kk0 m0-3 + B kk0 ; drain F1(t) ; CVT A(t,kk1) ; BAR ; MFMA */ \
    _Pragma("unroll") for (int m = 0; m < 4; ++m)                              \
        a0[m] = *(const bf16x8*)(lds + aoff[m][0]);                            \
    _Pragma("unroll") for (int n = 0; n < 4; ++n)                              \
        b0[n] = *(const bf16x8*)(lds + boff[n][0]);                            \
    W1;                                                                        \
    CVT_A(1);                                                                  \
    LGKM0;                                                                     \
    BAR;                                                                       \
    __builtin_amdgcn_s_setprio(1);                                             \
    _Pragma("unroll") for (int m = 0; m < 4; ++m)                              \
      _Pragma("unroll") for (int n = 0; n < 4; ++n)                            \
        acc[m][n] = __builtin_amdgcn_mfma_f32_16x16x32_bf16(                   \
            a0[m], b0[n], acc[m][n], 0, 0, 0);                                 \
    __builtin_amdgcn_s_setprio(0);                                             \
    /* P2: frags kk0 m4-7 ; stage B(kk0,t+1), F(kk1,t+1) ; drain B1(t) */      \
    _Pragma("unroll") for (int m = 0; m < 4; ++m)                              \
        a1[m] = *(const bf16x8*)(lds + aoff[4 + m][0]);                        \
    if (DO_STG) { STAGE_B(0, t_ + 1); STAGE_F(1, t_ + 1); }                    \
    W2;                                                                        \
    BAR;                                                                       \
    __builtin_amdgcn_s_setprio(1);                                             \
    _Pragma("unroll") for (int m = 0; m < 4; ++m)                              \
      _Pragma("unroll") for (int n = 0; n < 4; ++n)                            \
        acc[4 + m][n] = __builtin_amdgcn_mfma_f32_16x16x32_bf16(               \
            a1[m], b0[n], acc[4 + m][n], 0, 0, 0);                             \
    __builtin_amdgcn_s_setprio(0);                                             \
    /* P3: frags kk1 m0-3 + B kk1 ; drain F0(t+1) ; CVT A(t+1,kk0) ; BAR */    \
    _Pragma("unroll") for (int m = 0; m < 4; ++m)                              \
        a0[m] = *(const bf16x8*)(lds + aoff[m][1]);                            \
    _Pragma("unroll") for (int n = 0; n < 4; ++n)                              \
        b1[n] = *(const bf16x8*)(lds + boff[n][1]);                            \
    if (DO_CVT3) { W3; CVT_A(0); LGKM0; }                                      \
    BAR;                                                                       \
    __builtin_amdgcn_s_setprio(1);                                             \
    _Pragma("unroll") for (int m = 0; m < 4; ++m)                              \
      _Pragma("unroll") for (int n = 0; n < 4; ++n)                            \
        acc[m][n] = __builtin_amdgcn_mfma_f32_16x16x32_bf16(                   \
            a0[m], b1[n], acc[m][n], 0, 0, 0);                                 \
    __builtin_amdgcn_s_setprio(0);                                             \
    /* P4: frags kk1 m4-7 ; stage B(kk1,t+1), F(kk0,t+2) ; drain B0(t+1) */    \
    _Pragma("unroll") for (int m = 0; m < 4; ++m)                              \
        a1[m] = *(const bf16x8*)(lds + aoff[4 + m][1]);                        \
    if (DO_STG) {                                                              \
      STAGE_B(1, t_ + 1);                                                      \
      if (DO_F0) { STAGE_F(0, t_ + 2); }                                       \
      W4;                                                                      \
    }                                                                          \
    if (DO_BAR4) { BAR; }                                                      \
    __builtin_amdgcn_s_setprio(1);                                             \
    _Pragma("unroll") for (int m = 0; m < 4; ++m)                              \
      _Pragma("unroll") for (int n = 0; n < 4; ++n)                            \
        acc[4 + m][n] = __builtin_amdgcn_mfma_f32_16x16x32_bf16(               \
            a1[m], b1[n], acc[4 + m][n], 0, 0, 0);                             \
    __builtin_amdgcn_s_setprio(0);                                             \
  } while (0)

#pragma unroll 1
  for (int t = 0; t < NT - 2; ++t)
    TILE_STEP(t, 1, 1, 1, VMCNT(6), VMCNT(10), VMCNT(6), VMCNT(10), 1);
  // PEN: full stages except F(kk0,NT); W4 queue = [B0'2,F1'4,B1'2] -> drain B0'
  TILE_STEP(NT - 2, 1, 0, 1, VMCNT(6), VMCNT(10), VMCNT(6), VMCNT(6), 1);
  // LAST: no stages; W1 queue=[F1 4,B1 2]->VMCNT(2); W2 drains B1; no P3 cvt
  TILE_STEP(NT - 1, 0, 0, 0, VMCNT(2), VMCNT(0), (void)0, (void)0, 0);

  // ---- epilogue: fast-tanh + w_score partial dot, reduce over n (lane&15)
  const int nbase = nt * 256 + wc * 64;
  float wj[4], bj[4];
#pragma unroll
  for (int j = 0; j < 4; ++j) {
    int n = nbase + j * 16 + frow;
    wj[j] = w_score[n];
    bj[j] = bias[n];
  }
  const int mbase = mt * 256 + wr * 128;
  const int pidx = nt * 4 + wc;
#pragma unroll
  for (int i = 0; i < 8; ++i) {
#pragma unroll
    for (int r = 0; r < 4; ++r) {
      float v = 0.f;
#pragma unroll
      for (int j = 0; j < 4; ++j) v += wj[j] * tanh_fast(acc[i][j][r] + bj[j]);
      v += __shfl_xor(v, 1);
      v += __shfl_xor(v, 2);
      v += __shfl_xor(v, 4);
      v += __shfl_xor(v, 8);
      if (frow == 0) {
        int m = mbase + i * 16 + (lane >> 4) * 4 + r;
        spart[(size_t)m * 16 + pidx] = v;
      }
    }
  }
#undef TILE_STEP
#undef STAGE_B
#undef STAGE_F
#undef CVT_A
}

// ---------------------------------------------------------------- softmax over L per batch
__global__ void __launch_bounds__(256)
softmax_kernel(const float* __restrict__ spart, const float* __restrict__ b_score_p,
               float* __restrict__ attn) {
  const int b = blockIdx.x;
  const int tid = threadIdx.x;
  const int lane = tid & 63;
  const int w = tid >> 6;
  const float bsc = b_score_p[0];
  __shared__ float red[8];
  float s[8];
  float lmax = -1e30f;
#pragma unroll
  for (int u = 0; u < 8; ++u) {
    const int l = u * 256 + tid;
    const float4* p = (const float4*)(spart + ((size_t)b * 2048 + l) * 16);
    float4 a = p[0], c = p[1], d2 = p[2], e2 = p[3];
    float sum = bsc + a.x + a.y + a.z + a.w + c.x + c.y + c.z + c.w +
                d2.x + d2.y + d2.z + d2.w + e2.x + e2.y + e2.z + e2.w;
    s[u] = sum;
    lmax = fmaxf(lmax, sum);
  }
#pragma unroll
  for (int m = 32; m >= 1; m >>= 1) lmax = fmaxf(lmax, __shfl_xor(lmax, m));
  if (lane == 0) red[w] = lmax;
  __syncthreads();
  const float gmax = fmaxf(fmaxf(red[0], red[1]), fmaxf(red[2], red[3]));
  float e[8];
  float lsum = 0.f;
#pragma unroll
  for (int u = 0; u < 8; ++u) {
    e[u] = expf(s[u] - gmax);
    lsum += e[u];
  }
#pragma unroll
  for (int m = 32; m >= 1; m >>= 1) lsum += __shfl_xor(lsum, m);
  if (lane == 0) red[4 + w] = lsum;
  __syncthreads();
  const float inv = 1.f / (red[4] + red[5] + red[6] + red[7]);
#pragma unroll
  for (int u = 0; u < 8; ++u) attn[(size_t)b * 2048 + u * 256 + tid] = e[u] * inv;
}

// ---------------------------------------------------------------- context (f32 key, 32B/lane loads)
__global__ void __launch_bounds__(256)
ctx_part_kernel(const float* __restrict__ key, const float* __restrict__ attn,
                float* __restrict__ pctx) {
  __shared__ float a_sh[64];
  const int lc = blockIdx.x;   // 0..31
  const int b = blockIdx.y;    // 0..31
  const int tid = threadIdx.x;
  if (tid < 64) a_sh[tid] = attn[(size_t)b * 2048 + lc * 64 + tid];
  __syncthreads();
  const int ro = tid >> 7;            // 0..1
  const int h0 = (tid & 127) * 8;
  float ax[8] = {};
  const float* base =
      key + ((size_t)b * 2048 + lc * 64 + ro) * 1024 + h0;
#pragma unroll 4
  for (int li = 0; li < 32; ++li) {
    float a = a_sh[li * 2 + ro];
    float4 v0 = *(const float4*)(base + (size_t)li * 2048);
    float4 v1 = *(const float4*)(base + (size_t)li * 2048 + 4);
    ax[0] += a * v0.x; ax[1] += a * v0.y; ax[2] += a * v0.z; ax[3] += a * v0.w;
    ax[4] += a * v1.x; ax[5] += a * v1.y; ax[6] += a * v1.z; ax[7] += a * v1.w;
  }
  float* out = pctx + (((size_t)b * 32 + lc) * 2 + ro) * 1024 + h0;
#pragma unroll
  for (int j = 0; j < 8; ++j) out[j] = ax[j];
}

__global__ void __launch_bounds__(256)
ctx_reduce_kernel(const float* __restrict__ pctx, float* __restrict__ ctx) {
  const int idx = blockIdx.x * 256 + threadIdx.x;  // 0..32767
  const int b = idx >> 10, h = idx & 1023;
  float s = 0.f;
#pragma unroll
  for (int q = 0; q < 64; ++q) s += pctx[((size_t)b * 64 + q) * 1024 + h];
  ctx[idx] = s;
}

// ---------------------------------------------------------------- launch
extern "C" void kernel_launch(void* const* d_in, const int* in_sizes, int n_in,
                              void* d_out, int out_size, void* d_ws, size_t ws_size,
                              hipStream_t stream) {
  const float* query = (const float*)d_in[0];
  const float* key = (const float*)d_in[1];
  const float* Wq = (const float*)d_in[2];
  const float* Wk = (const float*)d_in[3];
  const float* bias = (const float*)d_in[4];
  const float* w_score = (const float*)d_in[5];
  const float* b_score = (const float*)d_in[6];

  float* out_ctx = (float*)d_out;
  float* out_attn = out_ctx + 32768;

  char* ws = (char*)d_ws;
  __hip_bfloat16* wkb = (__hip_bfloat16*)ws;                    // 2 MiB
  __hip_bfloat16* wqb = (__hip_bfloat16*)(ws + 2097152);        // 2 MiB
  float* spart = (float*)(ws + 4194304);                        // 4 MiB
  float* pctx = (float*)(ws + 8388608);                         // 8 MiB

  hipFuncSetAttribute((const void*)gemm_score_kernel,
                      hipFuncAttributeMaxDynamicSharedMemorySize, 131072);

  convert_w<<<2048, 256, 0, stream>>>(Wk, Wq, wkb, wqb);

  gemm_score_kernel<<<1024, 512, 131072, stream>>>(key, query, wkb, wqb, bias,
                                                   w_score, spart);

  softmax_kernel<<<B_DIM, 256, 0, stream>>>(spart, b_score, out_attn);

  ctx_part_kernel<<<dim3(32, B_DIM), 256, 0, stream>>>(key, out_attn, pctx);
  ctx_reduce_kernel<<<128, 256, 0, stream>>>(pctx, out_ctx);
}

// Round 8
// 476.163 us; speedup vs baseline: 1.0507x; 1.0507x over previous
//
#include <hip/hip_runtime.h>
#include <hip/hip_bf16.h>
#include <cstdint>

typedef __attribute__((ext_vector_type(8))) short bf16x8;
typedef __attribute__((ext_vector_type(4))) float f32x4;
typedef __attribute__((ext_vector_type(16))) float f32x16;

#define H_DIM 1024
#define B_DIM 32
#define L_DIM 2048
#define M_TOT (B_DIM * L_DIM)   // 65536
#define K_TOT (2 * H_DIM)       // 2048
#define NT 32                   // K-tiles of 64

__device__ __forceinline__ void gload16(const void* g, void* l) {
  __builtin_amdgcn_global_load_lds(
      (const __attribute__((address_space(1))) unsigned int*)g,
      (__attribute__((address_space(3))) unsigned int*)l, 16, 0, 0);
}

#define VMCNT(n) asm volatile("s_waitcnt vmcnt(" #n ")" ::: "memory")
#define SBAR __builtin_amdgcn_sched_barrier(0)
#define BAR do { SBAR; __builtin_amdgcn_s_barrier(); SBAR; } while (0)

// fast tanh: 1 - 2/(exp(2x)+1). Saturates correctly; no NaN. Validated R12.
__device__ __forceinline__ float tanh_fast(float x) {
  return 1.f - 2.f / (__expf(2.f * x) + 1.f);
}

// Balanced LDS swizzle (R8): byte ^= ((b8^b10)<<4) | ((b7^b9)<<5).
// Position-in-128B = {r&1, c_b1^r1^r3, c_b0^r2^r4} (r=row=byte>>6, c=16B chunk).
// For ANY 32-consecutive-row x fixed-chunk read (32x32 frags, both hi halves)
// this maps exactly 8 lanes per 128B position — the same uniformity as the
// measured-zero-conflict 16x16 pattern. Involution touching only bits 4-5;
// row & 16B interior untouched, so stage-source/read pairing stays exact.
// (Old swizzle ((byte>>7)&3)<<4 gave 4-way conflicts on 32-row reads: 2.5e7
// measured in R5.)
__device__ __forceinline__ int swz(int b) {
  return b ^ ((((b >> 8) ^ (b >> 10)) & 1) << 4) ^ ((((b >> 7) ^ (b >> 9)) & 1) << 5);
}

// ---------------------------------------------------------------- fused convert
__global__ void __launch_bounds__(256)
convert_all(const float* __restrict__ key, const float* __restrict__ query,
            const float* __restrict__ Wk, const float* __restrict__ Wq,
            __hip_bfloat16* __restrict__ keyb, __hip_bfloat16* __restrict__ qryb,
            __hip_bfloat16* __restrict__ wkb, __hip_bfloat16* __restrict__ wqb) {
  const int stride = gridDim.x * blockDim.x;
  for (int i = blockIdx.x * blockDim.x + threadIdx.x; i < 34078720; i += stride) {
    const float* src;
    __hip_bfloat16* dst;
    int off;
    if (i < 16777216)      { src = key;   dst = keyb; off = i; }
    else if (i < 33554432) { src = query; dst = qryb; off = i - 16777216; }
    else if (i < 33816576) { src = Wk;    dst = wkb;  off = i - 33554432; }
    else                   { src = Wq;    dst = wqb;  off = i - 33816576; }
    float4 v = ((const float4*)src)[off];
    __hip_bfloat16 h[4];
    h[0] = __float2bfloat16(v.x);
    h[1] = __float2bfloat16(v.y);
    h[2] = __float2bfloat16(v.z);
    h[3] = __float2bfloat16(v.w);
    *(uint2*)(dst + (size_t)off * 4) = *(const uint2*)h;
  }
}

// ---------------------------------------------------------------- 256x256x64 8-wave GEMM (R8: R11 schedule + 32x32x16 + balanced swizzle)
// R11 schedule (proven 273 us): one barrier per phase; stage P1->AK0, P2->BK0,
// P3->AK1, P4->BK1 of tile t+1; vmcnt(4)@P2/P4, never 0 mid-loop.
// MFMA 32x32x16 (denser pipe: 2495 vs 2176 TF ceiling; 8 instr/phase) — R5
// showed its frag layout + epilogue are CORRECT (passed) but the old swizzle
// caused 4-way bank conflicts (2.5e7); this round fixes only the swizzle.
// Fragment layouts (HW-verified m74/m101): A/B: row|col=lane&31,
// k=(lane>>5)*8+j. C/D: col=lane&31, row=(reg&3)+8*(reg>>2)+4*(lane>>5).
// LDS (128 KiB): A parity p at p*32768 (two 16KB halves [kk][256r][32c] bf16,
// 64B rows); B at 65536 + p*32768.
__global__ void __launch_bounds__(512, 2)
gemm_score_kernel(const __hip_bfloat16* __restrict__ keyb,
                  const __hip_bfloat16* __restrict__ qryb,
                  const __hip_bfloat16* __restrict__ wkb,
                  const __hip_bfloat16* __restrict__ wqb,
                  const float* __restrict__ bias,
                  const float* __restrict__ w_score,
                  float* __restrict__ spart) {
  extern __shared__ __align__(1024) char lds[];

  // bijective XCD swizzle: nwg=1024 (%8==0), chunk=128
  const int d = blockIdx.x;
  const int orig = (d & 7) * 128 + (d >> 3);
  const int mt = orig >> 2;  // 0..255
  const int nt = orig & 3;   // 0..3

  const int tid = threadIdx.x;
  const int lane = tid & 63;
  const int w = tid >> 6;
  const int wr = w >> 2;     // 0..1
  const int wc = w & 3;      // 0..3

  // ---- staging precompute: 2 loads of 16B per thread per 16KB half.
  int dstoff[2];
  size_t aoffg[2], boffg[2];
#pragma unroll
  for (int i = 0; i < 2; ++i) {
    int p = (i * 512 + tid) * 16;
    int row = p >> 6;                       // 0..255
    int q = swz(p);
    int col = (q & 63) >> 1;                // 0..31
    dstoff[i] = p;
    aoffg[i] = (size_t)(mt * 256 + row) * 1024 + col;
    boffg[i] = (size_t)(nt * 256 + row) * 1024 + col;
  }

#define STAGE_A(kk, tt) do {                                                   \
    const __hip_bfloat16* sp_ = ((tt) * 64 < 1024) ? keyb : qryb;              \
    const int kb_ = (((tt) * 64) & 1023) + (kk) * 32;                          \
    char* db_ = lds + ((tt) & 1) * 32768 + (kk) * 16384;                       \
    gload16(sp_ + aoffg[0] + kb_, db_ + dstoff[0]);                            \
    gload16(sp_ + aoffg[1] + kb_, db_ + dstoff[1]);                            \
  } while (0)
#define STAGE_B(kk, tt) do {                                                   \
    const __hip_bfloat16* sp_ = ((tt) * 64 < 1024) ? wkb : wqb;                \
    const int kb_ = (((tt) * 64) & 1023) + (kk) * 32;                          \
    char* db_ = lds + 65536 + ((tt) & 1) * 32768 + (kk) * 16384;               \
    gload16(sp_ + boffg[0] + kb_, db_ + dstoff[0]);                            \
    gload16(sp_ + boffg[1] + kb_, db_ + dstoff[1]);                            \
  } while (0)

  // ---- fragment ds_read byte offsets for 32x32x16 frags.
  // k4 = 0..3 indexes K-16-chunks within the K=64 tile; half = k4>>1.
  const int col32 = lane & 31;
  const int hi = lane >> 5;
  int aoff[4][4], boff[2][4];
#pragma unroll
  for (int mb = 0; mb < 4; ++mb) {
    int r = wr * 128 + mb * 32 + col32;
#pragma unroll
    for (int k4 = 0; k4 < 4; ++k4) {
      int byte = r * 64 + hi * 16 + (k4 & 1) * 32;
      aoff[mb][k4] = (k4 >> 1) * 16384 + swz(byte);
    }
  }
#pragma unroll
  for (int nb = 0; nb < 2; ++nb) {
    int rn = wc * 64 + nb * 32 + col32;
#pragma unroll
    for (int k4 = 0; k4 < 4; ++k4) {
      int byte = rn * 64 + hi * 16 + (k4 & 1) * 32;
      boff[nb][k4] = 65536 + (k4 >> 1) * 16384 + swz(byte);
    }
  }

  f32x16 acc[4][2] = {};

  // ---- prologue: stage all 4 halves of tile 0 (FIFO order = read order)
  STAGE_A(0, 0); STAGE_B(0, 0); STAGE_A(1, 0); STAGE_B(1, 0);
  VMCNT(4);          // AK0(0),BK0(0) landed; AK1(0),BK1(0) in flight
  BAR;

#define TILE_STEP(T, DO_S, W2, W4, DO_BAR4)                                    \
  do {                                                                         \
    const int t_ = (T);                                                        \
    const char* Ab = lds + (t_ & 1) * 32768;                                   \
    bf16x8 aA[2][2], aB[2][2], bb[2][2];                                       \
    /* P1: reads kk0: A mb0-1 + B nb0-1 (k4 0-1) ; stage AK0(t+1) ; BAR */     \
    _Pragma("unroll") for (int mb = 0; mb < 2; ++mb)                           \
      _Pragma("unroll") for (int j = 0; j < 2; ++j)                            \
        aA[mb][j] = *(const bf16x8*)(Ab + aoff[mb][j]);                        \
    _Pragma("unroll") for (int nb = 0; nb < 2; ++nb)                           \
      _Pragma("unroll") for (int j = 0; j < 2; ++j)                            \
        bb[nb][j] = *(const bf16x8*)(Ab + boff[nb][j]);                        \
    if (DO_S) { STAGE_A(0, t_ + 1); }                                          \
    BAR;                                                                       \
    __builtin_amdgcn_s_setprio(1);                                             \
    _Pragma("unroll") for (int mb = 0; mb < 2; ++mb)                           \
      _Pragma("unroll") for (int nb = 0; nb < 2; ++nb)                         \
        _Pragma("unroll") for (int j = 0; j < 2; ++j)                          \
          acc[mb][nb] = __builtin_amdgcn_mfma_f32_32x32x16_bf16(               \
              aA[mb][j], bb[nb][j], acc[mb][nb], 0, 0, 0);                     \
    __builtin_amdgcn_s_setprio(0);                                             \
    /* P2: reads kk0: A mb2-3 ; stage BK0(t+1) ; vmcnt ; BAR ; MFMA */         \
    _Pragma("unroll") for (int mb = 0; mb < 2; ++mb)                           \
      _Pragma("unroll") for (int j = 0; j < 2; ++j)                            \
        aB[mb][j] = *(const bf16x8*)(Ab + aoff[2 + mb][j]);                    \
    if (DO_S) { STAGE_B(0, t_ + 1); }                                          \
    W2;                                                                        \
    BAR;                                                                       \
    __builtin_amdgcn_s_setprio(1);                                             \
    _Pragma("unroll") for (int mb = 0; mb < 2; ++mb)                           \
      _Pragma("unroll") for (int nb = 0; nb < 2; ++nb)                         \
        _Pragma("unroll") for (int j = 0; j < 2; ++j)                          \
          acc[2 + mb][nb] = __builtin_amdgcn_mfma_f32_32x32x16_bf16(           \
              aB[mb][j], bb[nb][j], acc[2 + mb][nb], 0, 0, 0);                 \
    __builtin_amdgcn_s_setprio(0);                                             \
    /* P3: reads kk1: A mb0-1 + B nb0-1 (k4 2-3) ; stage AK1(t+1) ; BAR */     \
    _Pragma("unroll") for (int mb = 0; mb < 2; ++mb)                           \
      _Pragma("unroll") for (int j = 0; j < 2; ++j)                            \
        aA[mb][j] = *(const bf16x8*)(Ab + aoff[mb][2 + j]);                    \
    _Pragma("unroll") for (int nb = 0; nb < 2; ++nb)                           \
      _Pragma("unroll") for (int j = 0; j < 2; ++j)                            \
        bb[nb][j] = *(const bf16x8*)(Ab + boff[nb][2 + j]);                    \
    if (DO_S) { STAGE_A(1, t_ + 1); }                                          \
    BAR;                                                                       \
    __builtin_amdgcn_s_setprio(1);                                             \
    _Pragma("unroll") for (int mb = 0; mb < 2; ++mb)                           \
      _Pragma("unroll") for (int nb = 0; nb < 2; ++nb)                         \
        _Pragma("unroll") for (int j = 0; j < 2; ++j)                          \
          acc[mb][nb] = __builtin_amdgcn_mfma_f32_32x32x16_bf16(               \
              aA[mb][j], bb[nb][j], acc[mb][nb], 0, 0, 0);                     \
    __builtin_amdgcn_s_setprio(0);                                             \
    /* P4: reads kk1: A mb2-3 ; stage BK1(t+1) ; vmcnt ; BAR ; MFMA */         \
    _Pragma("unroll") for (int mb = 0; mb < 2; ++mb)                           \
      _Pragma("unroll") for (int j = 0; j < 2; ++j)                            \
        aB[mb][j] = *(const bf16x8*)(Ab + aoff[2 + mb][2 + j]);                \
    if (DO_S) { STAGE_B(1, t_ + 1); }                                          \
    W4;                                                                        \
    if (DO_BAR4) { BAR; }                                                      \
    __builtin_amdgcn_s_setprio(1);                                             \
    _Pragma("unroll") for (int mb = 0; mb < 2; ++mb)                           \
      _Pragma("unroll") for (int nb = 0; nb < 2; ++nb)                         \
        _Pragma("unroll") for (int j = 0; j < 2; ++j)                          \
          acc[2 + mb][nb] = __builtin_amdgcn_mfma_f32_32x32x16_bf16(           \
              aB[mb][j], bb[nb][j], acc[2 + mb][nb], 0, 0, 0);                 \
    __builtin_amdgcn_s_setprio(0);                                             \
  } while (0)

#pragma unroll 1
  for (int t = 0; t < NT - 1; ++t)
    TILE_STEP(t, true, VMCNT(4), VMCNT(4), true);
  TILE_STEP(NT - 1, false, VMCNT(0), (void)0, false);

  // ---- epilogue: fast-tanh + w_score partial dot, reduce over 32 cols
  // C/D layout: col=lane&31, row=(reg&3)+8*(reg>>2)+4*hi. (Validated R5.)
  const int nbase = nt * 256 + wc * 64;
  float wj[2], bj[2];
#pragma unroll
  for (int nb = 0; nb < 2; ++nb) {
    int n = nbase + nb * 32 + col32;
    wj[nb] = w_score[n];
    bj[nb] = bias[n];
  }
  const int mbase = mt * 256 + wr * 128;
  const int pidx = nt * 4 + wc;
#pragma unroll
  for (int mb = 0; mb < 4; ++mb) {
#pragma unroll
    for (int i = 0; i < 16; ++i) {
      float v = wj[0] * tanh_fast(acc[mb][0][i] + bj[0]) +
                wj[1] * tanh_fast(acc[mb][1][i] + bj[1]);
      v += __shfl_xor(v, 1);
      v += __shfl_xor(v, 2);
      v += __shfl_xor(v, 4);
      v += __shfl_xor(v, 8);
      v += __shfl_xor(v, 16);
      if (col32 == 0) {
        int m = mbase + mb * 32 + (i & 3) + 8 * (i >> 2) + 4 * hi;
        spart[(size_t)m * 16 + pidx] = v;
      }
    }
  }
#undef TILE_STEP
#undef STAGE_A
#undef STAGE_B
}

// ---------------------------------------------------------------- softmax over L per batch
__global__ void __launch_bounds__(256)
softmax_kernel(const float* __restrict__ spart, const float* __restrict__ b_score_p,
               float* __restrict__ attn) {
  const int b = blockIdx.x;
  const int tid = threadIdx.x;
  const int lane = tid & 63;
  const int w = tid >> 6;
  const float bsc = b_score_p[0];
  __shared__ float red[8];
  float s[8];
  float lmax = -1e30f;
#pragma unroll
  for (int u = 0; u < 8; ++u) {
    const int l = u * 256 + tid;
    const float4* p = (const float4*)(spart + ((size_t)b * 2048 + l) * 16);
    float4 a = p[0], c = p[1], d2 = p[2], e2 = p[3];
    float sum = bsc + a.x + a.y + a.z + a.w + c.x + c.y + c.z + c.w +
                d2.x + d2.y + d2.z + d2.w + e2.x + e2.y + e2.z + e2.w;
    s[u] = sum;
    lmax = fmaxf(lmax, sum);
  }
#pragma unroll
  for (int m = 32; m >= 1; m >>= 1) lmax = fmaxf(lmax, __shfl_xor(lmax, m));
  if (lane == 0) red[w] = lmax;
  __syncthreads();
  const float gmax = fmaxf(fmaxf(red[0], red[1]), fmaxf(red[2], red[3]));
  float e[8];
  float lsum = 0.f;
#pragma unroll
  for (int u = 0; u < 8; ++u) {
    e[u] = expf(s[u] - gmax);
    lsum += e[u];
  }
#pragma unroll
  for (int m = 32; m >= 1; m >>= 1) lsum += __shfl_xor(lsum, m);
  if (lane == 0) red[4 + w] = lsum;
  __syncthreads();
  const float inv = 1.f / (red[4] + red[5] + red[6] + red[7]);
#pragma unroll
  for (int u = 0; u < 8; ++u) attn[(size_t)b * 2048 + u * 256 + tid] = e[u] * inv;
}

// ---------------------------------------------------------------- context (bf16 key, 16B/lane loads)
__global__ void __launch_bounds__(256)
ctx_part_kernel(const __hip_bfloat16* __restrict__ keyb, const float* __restrict__ attn,
                float* __restrict__ pctx) {
  __shared__ float a_sh[256];
  const int lc = blockIdx.x;   // 0..7
  const int b = blockIdx.y;    // 0..31
  const int tid = threadIdx.x;
  a_sh[tid] = attn[(size_t)b * 2048 + lc * 256 + tid];
  __syncthreads();
  const int ro = tid >> 7;            // 0..1
  const int h0 = (tid & 127) * 8;
  float ax[8] = {};
  const __hip_bfloat16* base =
      keyb + ((size_t)b * 2048 + lc * 256 + ro) * 1024 + h0;
#pragma unroll 4
  for (int li = 0; li < 128; ++li) {
    float a = a_sh[li * 2 + ro];
    bf16x8 kv = *(const bf16x8*)(base + (size_t)li * 2048);
#pragma unroll
    for (int j = 0; j < 8; ++j) {
      unsigned uv = ((unsigned)(unsigned short)kv[j]) << 16;
      ax[j] += a * __uint_as_float(uv);
    }
  }
  float* out = pctx + (((size_t)b * 8 + lc) * 2 + ro) * 1024 + h0;
#pragma unroll
  for (int j = 0; j < 8; ++j) out[j] = ax[j];
}

__global__ void __launch_bounds__(256)
ctx_reduce_kernel(const float* __restrict__ pctx, float* __restrict__ ctx) {
  const int idx = blockIdx.x * 256 + threadIdx.x;  // 0..32767
  const int b = idx >> 10, h = idx & 1023;
  float s = 0.f;
#pragma unroll
  for (int q = 0; q < 16; ++q) s += pctx[((size_t)b * 16 + q) * 1024 + h];
  ctx[idx] = s;
}

// ---------------------------------------------------------------- launch
extern "C" void kernel_launch(void* const* d_in, const int* in_sizes, int n_in,
                              void* d_out, int out_size, void* d_ws, size_t ws_size,
                              hipStream_t stream) {
  const float* query = (const float*)d_in[0];
  const float* key = (const float*)d_in[1];
  const float* Wq = (const float*)d_in[2];
  const float* Wk = (const float*)d_in[3];
  const float* bias = (const float*)d_in[4];
  const float* w_score = (const float*)d_in[5];
  const float* b_score = (const float*)d_in[6];

  float* out_ctx = (float*)d_out;
  float* out_attn = out_ctx + 32768;

  char* ws = (char*)d_ws;
  const size_t MB128 = 134217728;
  __hip_bfloat16* keyb = (__hip_bfloat16*)ws;
  __hip_bfloat16* qryb = (__hip_bfloat16*)(ws + MB128);
  __hip_bfloat16* wkb = (__hip_bfloat16*)(ws + 2 * MB128);
  __hip_bfloat16* wqb = (__hip_bfloat16*)(ws + 2 * MB128 + 2097152);
  float* spart = (float*)(ws + 2 * MB128 + 4194304);            // 4 MiB
  float* pctx = (float*)(ws + 2 * MB128 + 8388608);             // 2 MiB

  hipFuncSetAttribute((const void*)gemm_score_kernel,
                      hipFuncAttributeMaxDynamicSharedMemorySize, 131072);

  convert_all<<<16384, 256, 0, stream>>>(key, query, Wk, Wq, keyb, qryb, wkb, wqb);

  gemm_score_kernel<<<1024, 512, 131072, stream>>>(keyb, qryb, wkb, wqb, bias,
                                                   w_score, spart);

  softmax_kernel<<<B_DIM, 256, 0, stream>>>(spart, b_score, out_attn);

  ctx_part_kernel<<<dim3(8, B_DIM), 256, 0, stream>>>(keyb, out_attn, pctx);
  ctx_reduce_kernel<<<128, 256, 0, stream>>>(pctx, out_ctx);
}